// Round 23
// baseline (390.787 us; speedup 1.0000x reference)
//
#include <hip/hip_runtime.h>
#include <hip/hip_fp16.h>

#define N_NODES 100000
#define N_EDGES 3200000
#define C 50
#define PH 64          // fp16 row stride for h/agg (128 B, line-aligned)
#define NH (N_NODES * PH)
#define NTILES (N_NODES / 16)                 // 6250
#define NB2 391                               // 256-node buckets
#define BSH2 8
#define BMSK2 255
#define BCAP2 9216
#define EPB 2048
#define EB  ((N_EDGES + EPB - 1) / EPB)       // 1563
#define EPT (EPB / 256)                       // 8

typedef _Float16 half8 __attribute__((ext_vector_type(8)));
typedef float floatx4 __attribute__((ext_vector_type(4)));

// ---------------- bucket-sorted CSR build ----------------

__global__ __launch_bounds__(256) void partition_kernel(const int* __restrict__ ei,
                                                        int* __restrict__ cnt,
                                                        unsigned int* __restrict__ pairs) {
    __shared__ int hist[NB2];
    __shared__ int base[NB2];
    int e0 = blockIdx.x * EPB;
    int b[EPT]; unsigned int p[EPT];
#pragma unroll
    for (int i = 0; i < EPT; ++i) {
        int e = e0 + i * 256 + threadIdx.x;
        bool ok = e < N_EDGES;
        int d = ok ? ei[N_EDGES + e] : 0;
        int s = ok ? ei[e] : 0;
        b[i] = ok ? (d >> BSH2) : -1;
        p[i] = ((unsigned)s << BSH2) | (unsigned)(d & BMSK2);
    }
    for (int t = threadIdx.x; t < NB2; t += 256) hist[t] = 0;
    __syncthreads();
#pragma unroll
    for (int i = 0; i < EPT; ++i)
        if (b[i] >= 0) atomicAdd(&hist[b[i]], 1);
    __syncthreads();
    for (int t = threadIdx.x; t < NB2; t += 256)
        base[t] = hist[t] ? (t * BCAP2 + atomicAdd(&cnt[t], hist[t])) : 0;
    __syncthreads();
    for (int t = threadIdx.x; t < NB2; t += 256) hist[t] = 0;
    __syncthreads();
#pragma unroll
    for (int i = 0; i < EPT; ++i) {
        if (b[i] >= 0) {
            int r = atomicAdd(&hist[b[i]], 1);
            pairs[base[b[i]] + r] = p[i];
        }
    }
}

__global__ __launch_bounds__(1024) void bscan_kernel(const int* __restrict__ cnt,
                                                     int* __restrict__ bucketOff) {
    __shared__ int buf[1024];
    int t = threadIdx.x;
    int v = (t < NB2) ? cnt[t] : 0;
    buf[t] = v;
    __syncthreads();
    for (int off = 1; off < 1024; off <<= 1) {
        int tv = (t >= off) ? buf[t - off] : 0;
        __syncthreads();
        buf[t] += tv;
        __syncthreads();
    }
    if (t < NB2) {
        int excl = buf[t] - v;
        bucketOff[t] = excl;
        if (t == NB2 - 1) bucketOff[NB2] = excl + v;
    }
}

__global__ __launch_bounds__(256) void bucket_fill_kernel(const unsigned int* __restrict__ pairs,
                                                          const int* __restrict__ cnt,
                                                          const int* __restrict__ bucketOff,
                                                          int* __restrict__ rowptr,
                                                          int* __restrict__ col) {
    __shared__ int deg[256];
    __shared__ int cur[256];
    int b = blockIdx.x;
    int nbase = b << BSH2;
    int n_e = cnt[b];
    int slot0 = b * BCAP2;
    int segB = bucketOff[b];
    int tid = threadIdx.x;
    deg[tid] = 0;
    __syncthreads();
    for (int e = tid; e < n_e; e += 256)
        atomicAdd(&deg[pairs[slot0 + e] & BMSK2], 1);
    __syncthreads();
    int v = deg[tid];
    cur[tid] = v;
    __syncthreads();
    for (int off = 1; off < 256; off <<= 1) {
        int t = (tid >= off) ? cur[tid - off] : 0;
        __syncthreads();
        cur[tid] += t;
        __syncthreads();
    }
    int excl = cur[tid] - v;
    int n = nbase + tid;
    if (n < N_NODES) rowptr[n] = segB + excl;
    __syncthreads();
    cur[tid] = excl;
    __syncthreads();
    for (int e = tid; e < n_e; e += 256) {
        unsigned int p = pairs[slot0 + e];
        int r = atomicAdd(&cur[p & BMSK2], 1);
        col[segB + r] = (int)(p >> BSH2);
    }
    if (b == 0 && tid == 0) rowptr[N_NODES] = N_EDGES;
}

// ---------------- fused setup: pad x, combined weights, cnt zero ----------------
// wb layout (13 x 4096 halves, B-frag row-major [n][64]):
//   0..8  : Wcomb[l][g][n][k] = sum_j conv_w[l][k][j] * w_ih[g*C+n][j]  (l*3+g)
//   9..11 : w_hh gates
//   12    : lin_w
__global__ __launch_bounds__(256) void init_kernel(const float* __restrict__ x,
                                                   const float* __restrict__ conv_w,
                                                   const float* __restrict__ w_ih,
                                                   const float* __restrict__ w_hh,
                                                   const float* __restrict__ lin_w,
                                                   _Float16* __restrict__ h0,
                                                   _Float16* __restrict__ wb,
                                                   int* __restrict__ cnt) {
    int t = blockIdx.x * 256 + threadIdx.x;
    if (t < NH) {
        int n = t >> 6, c = t & 63;
        h0[t] = (c < C) ? (_Float16)x[n * C + c] : (_Float16)0.f;
    }
    if (t < 13 * 4096) {
        int mat = t >> 12, idx = t & 4095, n = idx >> 6, k = idx & 63;
        float v = 0.f;
        if (n < C && k < C) {
            if (mat < 9) {
                int l = mat / 3, g = mat - l * 3;
                const float* wl = conv_w + l * C * C + k * C;     // W_l[k][:]
                const float* wi = w_ih + (g * C + n) * C;         // W_ih[g*C+n][:]
                float acc = 0.f;
#pragma unroll
                for (int j = 0; j < C; ++j) acc = fmaf(wl[j], wi[j], acc);
                v = acc;
            } else if (mat < 12) {
                v = w_hh[((mat - 9) * C + n) * C + k];
            } else {
                v = lin_w[n * C + k];
            }
        }
        wb[t] = (_Float16)v;
    }
    if (t < NB2) cnt[t] = 0;
}

// ---------------- MFMA helpers ----------------
__device__ inline half8 load_a16(const _Float16* __restrict__ base, int row, int ks, int lane) {
    return *(const half8*)(base + (size_t)row * PH + (ks << 5) + ((lane >> 4) << 3));
}

__device__ inline half8 load_b_frag(const _Float16* __restrict__ wb, int nt, int ks, int lane) {
    const _Float16* p = wb + (((nt << 4) + (lane & 15)) << 6) + (ks << 5) + ((lane >> 4) << 3);
    return *(const half8*)p;
}

// LDS B fragments: mat-major, row stride 72 halves (2-way bank alias, free)
__device__ inline half8 load_b_lds(const _Float16* swb, int mat, int nt, int ks, int lane) {
    return *(const half8*)(swb + mat * 4608 + ((nt << 4) + (lane & 15)) * 72 + (ks << 5) + ((lane >> 4) << 3));
}

__device__ inline float sigmoidf_(float x) { return 1.f / (1.f + __expf(-x)); }
__device__ inline float tanhf_(float x)    { return 2.f * sigmoidf_(2.f * x) - 1.f; }

// stage 6 B-matrices into LDS: 0..2 from ihp (layer-combined), 3..5 from hhp
__device__ inline void stage_swb(_Float16* swb, const _Float16* ihp, const _Float16* hhp) {
    for (int i = threadIdx.x; i < 3072; i += 256) {
        int g = i << 3;
        int m = g >> 12, rem = g & 4095, row = rem >> 6, colc = rem & 63;
        const _Float16* src = (m < 3) ? (ihp + g) : (hhp + (g - 3 * 4096));
        *(half8*)&swb[m * 4608 + row * 72 + colc] = *(const half8*)src;
    }
}

// ---------------- fused GRU (combined-conv weights; no conv stage) ----------------
__global__ __launch_bounds__(256) void gemm_gru(const _Float16* __restrict__ agg,
                                                const _Float16* __restrict__ hin,
                                                const _Float16* __restrict__ wb_ihc,
                                                const _Float16* __restrict__ wb_hh,
                                                const float* __restrict__ b_ih,
                                                const float* __restrict__ b_hh,
                                                _Float16* __restrict__ hout) {
    __shared__ __align__(16) _Float16 swb[6 * 4608];     // 55296 B
    __shared__ __align__(16) _Float16 hlds[4][16][72];   //  9216 B
    int wid = threadIdx.x >> 6, lane = threadIdx.x & 63;
    int tile = blockIdx.x * 4 + wid;
    bool act = tile < NTILES;
    int base = tile * 16;
    int lrow = lane & 15, lgrp = lane >> 4;
    stage_swb(swb, wb_ihc, wb_hh);
    half8 aA[2], aH[2];
    if (act) {
        int arow = base + lrow;
#pragma unroll
        for (int ks = 0; ks < 2; ++ks) {
            aA[ks] = load_a16(agg, arow, ks, lane);
            aH[ks] = load_a16(hin, arow, ks, lane);
        }
        *(half8*)&hlds[wid][lrow][lgrp << 3]        = aH[0];
        *(half8*)&hlds[wid][lrow][32 + (lgrp << 3)] = aH[1];
    }
    __syncthreads();
    if (!act) return;
#pragma unroll
    for (int nt = 0; nt < 4; ++nt) {
        int colc = (nt << 4) + lrow;
        bool cok = colc < C;
        float r_[4], z_[4];
        {
            floatx4 aI = {0.f,0.f,0.f,0.f}, aHc = {0.f,0.f,0.f,0.f};
#pragma unroll
            for (int ks = 0; ks < 2; ++ks) {
                aI  = __builtin_amdgcn_mfma_f32_16x16x32_f16(aA[ks], load_b_lds(swb, 0, nt, ks, lane), aI, 0, 0, 0);
                aHc = __builtin_amdgcn_mfma_f32_16x16x32_f16(aH[ks], load_b_lds(swb, 3, nt, ks, lane), aHc, 0, 0, 0);
            }
            float bi = cok ? b_ih[colc] : 0.f;
            float bh = cok ? b_hh[colc] : 0.f;
#pragma unroll
            for (int e = 0; e < 4; ++e) r_[e] = sigmoidf_((aI[e] + bi) + (aHc[e] + bh));
        }
        {
            floatx4 aI = {0.f,0.f,0.f,0.f}, aHc = {0.f,0.f,0.f,0.f};
#pragma unroll
            for (int ks = 0; ks < 2; ++ks) {
                aI  = __builtin_amdgcn_mfma_f32_16x16x32_f16(aA[ks], load_b_lds(swb, 1, nt, ks, lane), aI, 0, 0, 0);
                aHc = __builtin_amdgcn_mfma_f32_16x16x32_f16(aH[ks], load_b_lds(swb, 4, nt, ks, lane), aHc, 0, 0, 0);
            }
            float bi = cok ? b_ih[C + colc] : 0.f;
            float bh = cok ? b_hh[C + colc] : 0.f;
#pragma unroll
            for (int e = 0; e < 4; ++e) z_[e] = sigmoidf_((aI[e] + bi) + (aHc[e] + bh));
        }
        {
            floatx4 aI = {0.f,0.f,0.f,0.f}, aHc = {0.f,0.f,0.f,0.f};
#pragma unroll
            for (int ks = 0; ks < 2; ++ks) {
                aI  = __builtin_amdgcn_mfma_f32_16x16x32_f16(aA[ks], load_b_lds(swb, 2, nt, ks, lane), aI, 0, 0, 0);
                aHc = __builtin_amdgcn_mfma_f32_16x16x32_f16(aH[ks], load_b_lds(swb, 5, nt, ks, lane), aHc, 0, 0, 0);
            }
            float bi = cok ? b_ih[2 * C + colc] : 0.f;
            float bh = cok ? b_hh[2 * C + colc] : 0.f;
#pragma unroll
            for (int e = 0; e < 4; ++e) {
                int rl = (lgrp << 2) + e;
                int row = base + rl;
                _Float16 val = (_Float16)0.f;
                if (cok) {
                    float hv = (float)hlds[wid][rl][colc];
                    float nn = tanhf_((aI[e] + bi) + r_[e] * (aHc[e] + bh));
                    float z = z_[e];
                    val = (_Float16)((1.f - z) * nn + z * hv);
                }
                hout[(size_t)row * PH + colc] = val;
            }
        }
    }
}

// fused GRU + relu + output linear (h3 never materialized)
__global__ __launch_bounds__(256) void gemm_gru_out(const _Float16* __restrict__ agg,
                                                    const _Float16* __restrict__ hin,
                                                    const _Float16* __restrict__ wb_ihc,
                                                    const _Float16* __restrict__ wb_hh,
                                                    const float* __restrict__ b_ih,
                                                    const float* __restrict__ b_hh,
                                                    const _Float16* __restrict__ wb_out,
                                                    const float* __restrict__ lin_b,
                                                    float* __restrict__ out) {
    __shared__ __align__(16) _Float16 swb[6 * 4608];
    __shared__ __align__(16) _Float16 hlds[4][16][72];
    int wid = threadIdx.x >> 6, lane = threadIdx.x & 63;
    int tile = blockIdx.x * 4 + wid;
    bool act = tile < NTILES;
    int base = tile * 16;
    int lrow = lane & 15, lgrp = lane >> 4;
    stage_swb(swb, wb_ihc, wb_hh);
    half8 aA[2], aH[2];
    if (act) {
        int arow = base + lrow;
#pragma unroll
        for (int ks = 0; ks < 2; ++ks) {
            aA[ks] = load_a16(agg, arow, ks, lane);
            aH[ks] = load_a16(hin, arow, ks, lane);
        }
        *(half8*)&hlds[wid][lrow][lgrp << 3]        = aH[0];
        *(half8*)&hlds[wid][lrow][32 + (lgrp << 3)] = aH[1];
    }
    __syncthreads();
    if (act) {
#pragma unroll
        for (int nt = 0; nt < 4; ++nt) {
            int colc = (nt << 4) + lrow;
            bool cok = colc < C;
            float r_[4], z_[4];
            {
                floatx4 aI = {0.f,0.f,0.f,0.f}, aHc = {0.f,0.f,0.f,0.f};
#pragma unroll
                for (int ks = 0; ks < 2; ++ks) {
                    aI  = __builtin_amdgcn_mfma_f32_16x16x32_f16(aA[ks], load_b_lds(swb, 0, nt, ks, lane), aI, 0, 0, 0);
                    aHc = __builtin_amdgcn_mfma_f32_16x16x32_f16(aH[ks], load_b_lds(swb, 3, nt, ks, lane), aHc, 0, 0, 0);
                }
                float bi = cok ? b_ih[colc] : 0.f;
                float bh = cok ? b_hh[colc] : 0.f;
#pragma unroll
                for (int e = 0; e < 4; ++e) r_[e] = sigmoidf_((aI[e] + bi) + (aHc[e] + bh));
            }
            {
                floatx4 aI = {0.f,0.f,0.f,0.f}, aHc = {0.f,0.f,0.f,0.f};
#pragma unroll
                for (int ks = 0; ks < 2; ++ks) {
                    aI  = __builtin_amdgcn_mfma_f32_16x16x32_f16(aA[ks], load_b_lds(swb, 1, nt, ks, lane), aI, 0, 0, 0);
                    aHc = __builtin_amdgcn_mfma_f32_16x16x32_f16(aH[ks], load_b_lds(swb, 4, nt, ks, lane), aHc, 0, 0, 0);
                }
                float bi = cok ? b_ih[C + colc] : 0.f;
                float bh = cok ? b_hh[C + colc] : 0.f;
#pragma unroll
                for (int e = 0; e < 4; ++e) z_[e] = sigmoidf_((aI[e] + bi) + (aHc[e] + bh));
            }
            {
                floatx4 aI = {0.f,0.f,0.f,0.f}, aHc = {0.f,0.f,0.f,0.f};
#pragma unroll
                for (int ks = 0; ks < 2; ++ks) {
                    aI  = __builtin_amdgcn_mfma_f32_16x16x32_f16(aA[ks], load_b_lds(swb, 2, nt, ks, lane), aI, 0, 0, 0);
                    aHc = __builtin_amdgcn_mfma_f32_16x16x32_f16(aH[ks], load_b_lds(swb, 5, nt, ks, lane), aHc, 0, 0, 0);
                }
                float bi = cok ? b_ih[2 * C + colc] : 0.f;
                float bh = cok ? b_hh[2 * C + colc] : 0.f;
#pragma unroll
                for (int e = 0; e < 4; ++e) {
                    int rl = (lgrp << 2) + e;
                    _Float16 val = (_Float16)0.f;
                    if (cok) {
                        float hv = (float)hlds[wid][rl][colc];
                        float nn = tanhf_((aI[e] + bi) + r_[e] * (aHc[e] + bh));
                        float z = z_[e];
                        float h3 = (1.f - z) * nn + z * hv;
                        val = (_Float16)(h3 > 0.f ? h3 : 0.f);   // relu fused
                    }
                    hlds[wid][rl][colc] = val;
                }
            }
        }
    }
    __syncthreads();
    if (act) {
        half8 a0 = *(const half8*)&hlds[wid][lrow][lgrp << 3];
        half8 a1 = *(const half8*)&hlds[wid][lrow][32 + (lgrp << 3)];
#pragma unroll
        for (int nt = 0; nt < 4; ++nt) {
            floatx4 acc = {0.f, 0.f, 0.f, 0.f};
            acc = __builtin_amdgcn_mfma_f32_16x16x32_f16(a0, load_b_frag(wb_out, nt, 0, lane), acc, 0, 0, 0);
            acc = __builtin_amdgcn_mfma_f32_16x16x32_f16(a1, load_b_frag(wb_out, nt, 1, lane), acc, 0, 0, 0);
            int col = (nt << 4) + lrow;
            if (col < C) {
                float b = lin_b[col];
#pragma unroll
                for (int e = 0; e < 4; ++e) {
                    int row = base + (lgrp << 2) + e;
                    out[(size_t)row * C + col] = acc[e] + b;
                }
            }
        }
    }
}

// ---------------- gather raw h rows (conv folded into GRU weights) ----------------
__global__ __launch_bounds__(256) void gather_kernel(const __half* __restrict__ h,
                                                     const int* __restrict__ rowptr,
                                                     const int* __restrict__ col,
                                                     _Float16* __restrict__ agg) {
    int w = (blockIdx.x * 256 + threadIdx.x) >> 6;
    int lane = threadIdx.x & 63;
    if (w >= N_NODES) return;
    int start = rowptr[w], end = rowptr[w + 1];
    int j = lane >> 3, q = lane & 7;
    bool qok = (q < 7);
    int hoff = qok ? (q * 8) : 48;
    float acc0 = 0.f, acc1 = 0.f, acc2 = 0.f, acc3 = 0.f;
    float acc4 = 0.f, acc5 = 0.f, acc6 = 0.f, acc7 = 0.f;

    for (int base = start; base < end; base += 64) {
        int cidx = base + lane;
        int cols = col[cidx < N_EDGES ? cidx : (N_EDGES - 1)];
        int cnt = end - base; if (cnt > 64) cnt = 64;
        int nt8 = (cnt + 7) >> 3;
#pragma unroll 4
        for (int t = 0; t < nt8; ++t) {
            int rel = 8 * t + j;
            int s = __shfl(cols, rel);
            bool valid = qok && (rel < cnt);
            const uint4 v = *reinterpret_cast<const uint4*>(h + (size_t)s * PH + hoff);
            float2 f0 = __half22float2(*reinterpret_cast<const __half2*>(&v.x));
            float2 f1 = __half22float2(*reinterpret_cast<const __half2*>(&v.y));
            float2 f2 = __half22float2(*reinterpret_cast<const __half2*>(&v.z));
            float2 f3 = __half22float2(*reinterpret_cast<const __half2*>(&v.w));
            acc0 += valid ? f0.x : 0.f;  acc1 += valid ? f0.y : 0.f;
            acc2 += valid ? f1.x : 0.f;  acc3 += valid ? f1.y : 0.f;
            acc4 += valid ? f2.x : 0.f;  acc5 += valid ? f2.y : 0.f;
            acc6 += valid ? f3.x : 0.f;  acc7 += valid ? f3.y : 0.f;
        }
    }
#pragma unroll
    for (int s = 8; s <= 32; s <<= 1) {
        acc0 += __shfl_xor(acc0, s); acc1 += __shfl_xor(acc1, s);
        acc2 += __shfl_xor(acc2, s); acc3 += __shfl_xor(acc3, s);
        acc4 += __shfl_xor(acc4, s); acc5 += __shfl_xor(acc5, s);
        acc6 += __shfl_xor(acc6, s); acc7 += __shfl_xor(acc7, s);
    }
    if (j == 0) {
        if (qok) {
            half8 o;
            o[0] = (_Float16)acc0; o[1] = (_Float16)acc1;
            o[2] = (_Float16)acc2; o[3] = (_Float16)acc3;
            o[4] = (_Float16)acc4; o[5] = (_Float16)acc5;
            o[6] = (_Float16)acc6; o[7] = (_Float16)acc7;
            *reinterpret_cast<half8*>(agg + (size_t)w * PH + q * 8) = o;
        } else {
            half8 z = {};
            *reinterpret_cast<half8*>(agg + (size_t)w * PH + 56) = z;
        }
    }
}

extern "C" void kernel_launch(void* const* d_in, const int* in_sizes, int n_in,
                              void* d_out, int out_size, void* d_ws, size_t ws_size,
                              hipStream_t stream) {
    const float* x      = (const float*)d_in[0];
    const int*   ei     = (const int*)  d_in[1];
    const float* conv_w = (const float*)d_in[3];
    const float* w_ih   = (const float*)d_in[4];
    const float* w_hh   = (const float*)d_in[5];
    const float* b_ih   = (const float*)d_in[6];
    const float* b_hh   = (const float*)d_in[7];
    const float* lin_w  = (const float*)d_in[9];
    const float* lin_b  = (const float*)d_in[10];
    float* out = (float*)d_out;

    // layout: h0 | h1 | agg | scratch(NH) | wb | col | rowptr | cnt | off
    // pairs (14.4 MB) spans agg (12.8) + head of scratch — dead after fill; wb untouched
    _Float16* h0  = (_Float16*)d_ws;
    _Float16* h1  = h0 + NH;
    _Float16* agg = h1 + NH;
    _Float16* scratch = agg + NH;              // pairs overflow region
    _Float16* wb  = scratch + NH;
    unsigned int* pairs = (unsigned int*)agg;
    int* col       = (int*)(wb + 13 * 4096);
    int* rowptr    = col + N_EDGES;
    int* cnt       = rowptr + N_NODES + 1;
    int* bucketOff = cnt + NB2;

    const int initBlocks = (NH + 255) / 256;
    const int waveBlocks = (N_NODES * 64 + 255) / 256;
    const int gemmBlocks = (NTILES + 3) / 4;

    init_kernel<<<initBlocks, 256, 0, stream>>>(x, conv_w, w_ih, w_hh, lin_w, h0, wb, cnt);

    partition_kernel<<<EB, 256, 0, stream>>>(ei, cnt, pairs);
    bscan_kernel<<<1, 1024, 0, stream>>>(cnt, bucketOff);
    bucket_fill_kernel<<<NB2, 256, 0, stream>>>(pairs, cnt, bucketOff, rowptr, col);

    // layer 1: gather raw h0; GRU with W_l1-combined gate weights
    gather_kernel<<<waveBlocks, 256, 0, stream>>>((const __half*)h0, rowptr, col, agg);
    gemm_gru<<<gemmBlocks, 256, 0, stream>>>(agg, h0, wb + 0 * 3 * 4096, wb + 9 * 4096,
                                             b_ih, b_hh, h1);
    // layer 2
    gather_kernel<<<waveBlocks, 256, 0, stream>>>((const __half*)h1, rowptr, col, agg);
    gemm_gru<<<gemmBlocks, 256, 0, stream>>>(agg, h1, wb + 1 * 3 * 4096, wb + 9 * 4096,
                                             b_ih, b_hh, h0);
    // layer 3 + out
    gather_kernel<<<waveBlocks, 256, 0, stream>>>((const __half*)h0, rowptr, col, agg);
    gemm_gru_out<<<gemmBlocks, 256, 0, stream>>>(agg, h0, wb + 2 * 3 * 4096, wb + 9 * 4096,
                                                 b_ih, b_hh, wb + 12 * 4096, lin_b, out);
}

// Round 24
// 355.555 us; speedup vs baseline: 1.0991x; 1.0991x over previous
//
#include <hip/hip_runtime.h>
#include <hip/hip_fp16.h>

#define N_NODES 100000
#define N_EDGES 3200000
#define C 50
#define PH 64          // fp16 row stride for h/agg (128 B, line-aligned)
#define NH (N_NODES * PH)
#define NTILES (N_NODES / 16)                 // 6250
#define NB2 391                               // 256-node buckets
#define BSH2 8
#define BMSK2 255
#define BCAP2 9216
#define EPB 4096
#define EB  ((N_EDGES + EPB - 1) / EPB)       // 782
#define EPT (EPB / 256)                       // 16

typedef _Float16 half8 __attribute__((ext_vector_type(8)));
typedef float floatx4 __attribute__((ext_vector_type(4)));

// ---------------- bucket-sorted CSR build ----------------

__global__ __launch_bounds__(256) void partition_kernel(const int* __restrict__ ei,
                                                        int* __restrict__ cnt,
                                                        unsigned int* __restrict__ pairs) {
    __shared__ int hist[NB2];
    __shared__ int base[NB2];
    int e0 = blockIdx.x * EPB;
    int b[EPT]; unsigned int p[EPT];
#pragma unroll
    for (int i = 0; i < EPT; ++i) {
        int e = e0 + i * 256 + threadIdx.x;
        bool ok = e < N_EDGES;
        int d = ok ? ei[N_EDGES + e] : 0;
        int s = ok ? ei[e] : 0;
        b[i] = ok ? (d >> BSH2) : -1;
        p[i] = ((unsigned)s << BSH2) | (unsigned)(d & BMSK2);
    }
    for (int t = threadIdx.x; t < NB2; t += 256) hist[t] = 0;
    __syncthreads();
#pragma unroll
    for (int i = 0; i < EPT; ++i)
        if (b[i] >= 0) atomicAdd(&hist[b[i]], 1);
    __syncthreads();
    for (int t = threadIdx.x; t < NB2; t += 256)
        base[t] = hist[t] ? (t * BCAP2 + atomicAdd(&cnt[t], hist[t])) : 0;
    __syncthreads();
    for (int t = threadIdx.x; t < NB2; t += 256) hist[t] = 0;
    __syncthreads();
#pragma unroll
    for (int i = 0; i < EPT; ++i) {
        if (b[i] >= 0) {
            int r = atomicAdd(&hist[b[i]], 1);
            pairs[base[b[i]] + r] = p[i];
        }
    }
}

__global__ __launch_bounds__(1024) void bscan_kernel(const int* __restrict__ cnt,
                                                     int* __restrict__ bucketOff) {
    __shared__ int buf[1024];
    int t = threadIdx.x;
    int v = (t < NB2) ? cnt[t] : 0;
    buf[t] = v;
    __syncthreads();
    for (int off = 1; off < 1024; off <<= 1) {
        int tv = (t >= off) ? buf[t - off] : 0;
        __syncthreads();
        buf[t] += tv;
        __syncthreads();
    }
    if (t < NB2) {
        int excl = buf[t] - v;
        bucketOff[t] = excl;
        if (t == NB2 - 1) bucketOff[NB2] = excl + v;
    }
}

__global__ __launch_bounds__(256) void bucket_fill_kernel(const unsigned int* __restrict__ pairs,
                                                          const int* __restrict__ cnt,
                                                          const int* __restrict__ bucketOff,
                                                          int* __restrict__ rowptr,
                                                          int* __restrict__ col) {
    __shared__ int deg[256];
    __shared__ int cur[256];
    int b = blockIdx.x;
    int nbase = b << BSH2;
    int n_e = cnt[b];
    int slot0 = b * BCAP2;
    int segB = bucketOff[b];
    int tid = threadIdx.x;
    deg[tid] = 0;
    __syncthreads();
    for (int e = tid; e < n_e; e += 256)
        atomicAdd(&deg[pairs[slot0 + e] & BMSK2], 1);
    __syncthreads();
    int v = deg[tid];
    cur[tid] = v;
    __syncthreads();
    for (int off = 1; off < 256; off <<= 1) {
        int t = (tid >= off) ? cur[tid - off] : 0;
        __syncthreads();
        cur[tid] += t;
        __syncthreads();
    }
    int excl = cur[tid] - v;
    int n = nbase + tid;
    if (n < N_NODES) rowptr[n] = segB + excl;
    __syncthreads();
    cur[tid] = excl;
    __syncthreads();
    for (int e = tid; e < n_e; e += 256) {
        unsigned int p = pairs[slot0 + e];
        int r = atomicAdd(&cur[p & BMSK2], 1);
        col[segB + r] = (int)(p >> BSH2);
    }
    if (b == 0 && tid == 0) rowptr[N_NODES] = N_EDGES;
}

// ---------------- fused setup: pad x, combined weights, cnt zero ----------------
// wb layout (13 x 4096 halves, B-frag row-major [n][64]):
//   0..8  : Wcomb[l][g][n][k] = sum_j conv_w[l][k][j] * w_ih[g*C+n][j]  (l*3+g)
//   9..11 : w_hh gates
//   12    : lin_w
__global__ __launch_bounds__(256) void init_kernel(const float* __restrict__ x,
                                                   const float* __restrict__ conv_w,
                                                   const float* __restrict__ w_ih,
                                                   const float* __restrict__ w_hh,
                                                   const float* __restrict__ lin_w,
                                                   _Float16* __restrict__ h0,
                                                   _Float16* __restrict__ wb,
                                                   int* __restrict__ cnt) {
    int t = blockIdx.x * 256 + threadIdx.x;
    if (t < NH) {
        int n = t >> 6, c = t & 63;
        h0[t] = (c < C) ? (_Float16)x[n * C + c] : (_Float16)0.f;
    }
    if (t < 13 * 4096) {
        int mat = t >> 12, idx = t & 4095, n = idx >> 6, k = idx & 63;
        float v = 0.f;
        if (n < C && k < C) {
            if (mat < 9) {
                int l = mat / 3, g = mat - l * 3;
                const float* wl = conv_w + l * C * C + k * C;     // W_l[k][:]
                const float* wi = w_ih + (g * C + n) * C;         // W_ih[g*C+n][:]
                float acc = 0.f;
#pragma unroll
                for (int j = 0; j < C; ++j) acc = fmaf(wl[j], wi[j], acc);
                v = acc;
            } else if (mat < 12) {
                v = w_hh[((mat - 9) * C + n) * C + k];
            } else {
                v = lin_w[n * C + k];
            }
        }
        wb[t] = (_Float16)v;
    }
    if (t < NB2) cnt[t] = 0;
}

// ---------------- MFMA helpers ----------------
__device__ inline half8 load_a16(const _Float16* __restrict__ base, int row, int ks, int lane) {
    return *(const half8*)(base + (size_t)row * PH + (ks << 5) + ((lane >> 4) << 3));
}

__device__ inline half8 load_b_frag(const _Float16* __restrict__ wb, int nt, int ks, int lane) {
    const _Float16* p = wb + (((nt << 4) + (lane & 15)) << 6) + (ks << 5) + ((lane >> 4) << 3);
    return *(const half8*)p;
}

// LDS B fragments: mat-major, row stride 72 halves (2-way bank alias, free)
__device__ inline half8 load_b_lds(const _Float16* swb, int mat, int nt, int ks, int lane) {
    return *(const half8*)(swb + mat * 4608 + ((nt << 4) + (lane & 15)) * 72 + (ks << 5) + ((lane >> 4) << 3));
}

__device__ inline float sigmoidf_(float x) { return 1.f / (1.f + __expf(-x)); }
__device__ inline float tanhf_(float x)    { return 2.f * sigmoidf_(2.f * x) - 1.f; }

// stage 6 B-matrices into LDS: 0..2 from ihp (layer-combined), 3..5 from hhp
__device__ inline void stage_swb(_Float16* swb, const _Float16* ihp, const _Float16* hhp) {
    for (int i = threadIdx.x; i < 3072; i += 256) {
        int g = i << 3;
        int m = g >> 12, rem = g & 4095, row = rem >> 6, colc = rem & 63;
        const _Float16* src = (m < 3) ? (ihp + g) : (hhp + (g - 3 * 4096));
        *(half8*)&swb[m * 4608 + row * 72 + colc] = *(const half8*)src;
    }
}

// ---------------- fused GRU (combined-conv weights; no conv stage) ----------------
__global__ __launch_bounds__(256) void gemm_gru(const _Float16* __restrict__ agg,
                                                const _Float16* __restrict__ hin,
                                                const _Float16* __restrict__ wb_ihc,
                                                const _Float16* __restrict__ wb_hh,
                                                const float* __restrict__ b_ih,
                                                const float* __restrict__ b_hh,
                                                _Float16* __restrict__ hout) {
    __shared__ __align__(16) _Float16 swb[6 * 4608];     // 55296 B
    __shared__ __align__(16) _Float16 hlds[4][16][72];   //  9216 B
    int wid = threadIdx.x >> 6, lane = threadIdx.x & 63;
    int tile = blockIdx.x * 4 + wid;
    bool act = tile < NTILES;
    int base = tile * 16;
    int lrow = lane & 15, lgrp = lane >> 4;
    stage_swb(swb, wb_ihc, wb_hh);
    half8 aA[2], aH[2];
    if (act) {
        int arow = base + lrow;
#pragma unroll
        for (int ks = 0; ks < 2; ++ks) {
            aA[ks] = load_a16(agg, arow, ks, lane);
            aH[ks] = load_a16(hin, arow, ks, lane);
        }
        *(half8*)&hlds[wid][lrow][lgrp << 3]        = aH[0];
        *(half8*)&hlds[wid][lrow][32 + (lgrp << 3)] = aH[1];
    }
    __syncthreads();
    if (!act) return;
#pragma unroll
    for (int nt = 0; nt < 4; ++nt) {
        int colc = (nt << 4) + lrow;
        bool cok = colc < C;
        float r_[4], z_[4];
        {
            floatx4 aI = {0.f,0.f,0.f,0.f}, aHc = {0.f,0.f,0.f,0.f};
#pragma unroll
            for (int ks = 0; ks < 2; ++ks) {
                aI  = __builtin_amdgcn_mfma_f32_16x16x32_f16(aA[ks], load_b_lds(swb, 0, nt, ks, lane), aI, 0, 0, 0);
                aHc = __builtin_amdgcn_mfma_f32_16x16x32_f16(aH[ks], load_b_lds(swb, 3, nt, ks, lane), aHc, 0, 0, 0);
            }
            float bi = cok ? b_ih[colc] : 0.f;
            float bh = cok ? b_hh[colc] : 0.f;
#pragma unroll
            for (int e = 0; e < 4; ++e) r_[e] = sigmoidf_((aI[e] + bi) + (aHc[e] + bh));
        }
        {
            floatx4 aI = {0.f,0.f,0.f,0.f}, aHc = {0.f,0.f,0.f,0.f};
#pragma unroll
            for (int ks = 0; ks < 2; ++ks) {
                aI  = __builtin_amdgcn_mfma_f32_16x16x32_f16(aA[ks], load_b_lds(swb, 1, nt, ks, lane), aI, 0, 0, 0);
                aHc = __builtin_amdgcn_mfma_f32_16x16x32_f16(aH[ks], load_b_lds(swb, 4, nt, ks, lane), aHc, 0, 0, 0);
            }
            float bi = cok ? b_ih[C + colc] : 0.f;
            float bh = cok ? b_hh[C + colc] : 0.f;
#pragma unroll
            for (int e = 0; e < 4; ++e) z_[e] = sigmoidf_((aI[e] + bi) + (aHc[e] + bh));
        }
        {
            floatx4 aI = {0.f,0.f,0.f,0.f}, aHc = {0.f,0.f,0.f,0.f};
#pragma unroll
            for (int ks = 0; ks < 2; ++ks) {
                aI  = __builtin_amdgcn_mfma_f32_16x16x32_f16(aA[ks], load_b_lds(swb, 2, nt, ks, lane), aI, 0, 0, 0);
                aHc = __builtin_amdgcn_mfma_f32_16x16x32_f16(aH[ks], load_b_lds(swb, 5, nt, ks, lane), aHc, 0, 0, 0);
            }
            float bi = cok ? b_ih[2 * C + colc] : 0.f;
            float bh = cok ? b_hh[2 * C + colc] : 0.f;
#pragma unroll
            for (int e = 0; e < 4; ++e) {
                int rl = (lgrp << 2) + e;
                int row = base + rl;
                _Float16 val = (_Float16)0.f;
                if (cok) {
                    float hv = (float)hlds[wid][rl][colc];
                    float nn = tanhf_((aI[e] + bi) + r_[e] * (aHc[e] + bh));
                    float z = z_[e];
                    val = (_Float16)((1.f - z) * nn + z * hv);
                }
                hout[(size_t)row * PH + colc] = val;
            }
        }
    }
}

// fused GRU + relu + output linear (h3 never materialized)
__global__ __launch_bounds__(256) void gemm_gru_out(const _Float16* __restrict__ agg,
                                                    const _Float16* __restrict__ hin,
                                                    const _Float16* __restrict__ wb_ihc,
                                                    const _Float16* __restrict__ wb_hh,
                                                    const float* __restrict__ b_ih,
                                                    const float* __restrict__ b_hh,
                                                    const _Float16* __restrict__ wb_out,
                                                    const float* __restrict__ lin_b,
                                                    float* __restrict__ out) {
    __shared__ __align__(16) _Float16 swb[6 * 4608];
    __shared__ __align__(16) _Float16 hlds[4][16][72];
    int wid = threadIdx.x >> 6, lane = threadIdx.x & 63;
    int tile = blockIdx.x * 4 + wid;
    bool act = tile < NTILES;
    int base = tile * 16;
    int lrow = lane & 15, lgrp = lane >> 4;
    stage_swb(swb, wb_ihc, wb_hh);
    half8 aA[2], aH[2];
    if (act) {
        int arow = base + lrow;
#pragma unroll
        for (int ks = 0; ks < 2; ++ks) {
            aA[ks] = load_a16(agg, arow, ks, lane);
            aH[ks] = load_a16(hin, arow, ks, lane);
        }
        *(half8*)&hlds[wid][lrow][lgrp << 3]        = aH[0];
        *(half8*)&hlds[wid][lrow][32 + (lgrp << 3)] = aH[1];
    }
    __syncthreads();
    if (act) {
#pragma unroll
        for (int nt = 0; nt < 4; ++nt) {
            int colc = (nt << 4) + lrow;
            bool cok = colc < C;
            float r_[4], z_[4];
            {
                floatx4 aI = {0.f,0.f,0.f,0.f}, aHc = {0.f,0.f,0.f,0.f};
#pragma unroll
                for (int ks = 0; ks < 2; ++ks) {
                    aI  = __builtin_amdgcn_mfma_f32_16x16x32_f16(aA[ks], load_b_lds(swb, 0, nt, ks, lane), aI, 0, 0, 0);
                    aHc = __builtin_amdgcn_mfma_f32_16x16x32_f16(aH[ks], load_b_lds(swb, 3, nt, ks, lane), aHc, 0, 0, 0);
                }
                float bi = cok ? b_ih[colc] : 0.f;
                float bh = cok ? b_hh[colc] : 0.f;
#pragma unroll
                for (int e = 0; e < 4; ++e) r_[e] = sigmoidf_((aI[e] + bi) + (aHc[e] + bh));
            }
            {
                floatx4 aI = {0.f,0.f,0.f,0.f}, aHc = {0.f,0.f,0.f,0.f};
#pragma unroll
                for (int ks = 0; ks < 2; ++ks) {
                    aI  = __builtin_amdgcn_mfma_f32_16x16x32_f16(aA[ks], load_b_lds(swb, 1, nt, ks, lane), aI, 0, 0, 0);
                    aHc = __builtin_amdgcn_mfma_f32_16x16x32_f16(aH[ks], load_b_lds(swb, 4, nt, ks, lane), aHc, 0, 0, 0);
                }
                float bi = cok ? b_ih[C + colc] : 0.f;
                float bh = cok ? b_hh[C + colc] : 0.f;
#pragma unroll
                for (int e = 0; e < 4; ++e) z_[e] = sigmoidf_((aI[e] + bi) + (aHc[e] + bh));
            }
            {
                floatx4 aI = {0.f,0.f,0.f,0.f}, aHc = {0.f,0.f,0.f,0.f};
#pragma unroll
                for (int ks = 0; ks < 2; ++ks) {
                    aI  = __builtin_amdgcn_mfma_f32_16x16x32_f16(aA[ks], load_b_lds(swb, 2, nt, ks, lane), aI, 0, 0, 0);
                    aHc = __builtin_amdgcn_mfma_f32_16x16x32_f16(aH[ks], load_b_lds(swb, 5, nt, ks, lane), aHc, 0, 0, 0);
                }
                float bi = cok ? b_ih[2 * C + colc] : 0.f;
                float bh = cok ? b_hh[2 * C + colc] : 0.f;
#pragma unroll
                for (int e = 0; e < 4; ++e) {
                    int rl = (lgrp << 2) + e;
                    _Float16 val = (_Float16)0.f;
                    if (cok) {
                        float hv = (float)hlds[wid][rl][colc];
                        float nn = tanhf_((aI[e] + bi) + r_[e] * (aHc[e] + bh));
                        float z = z_[e];
                        float h3 = (1.f - z) * nn + z * hv;
                        val = (_Float16)(h3 > 0.f ? h3 : 0.f);   // relu fused
                    }
                    hlds[wid][rl][colc] = val;
                }
            }
        }
    }
    __syncthreads();
    if (act) {
        half8 a0 = *(const half8*)&hlds[wid][lrow][lgrp << 3];
        half8 a1 = *(const half8*)&hlds[wid][lrow][32 + (lgrp << 3)];
#pragma unroll
        for (int nt = 0; nt < 4; ++nt) {
            floatx4 acc = {0.f, 0.f, 0.f, 0.f};
            acc = __builtin_amdgcn_mfma_f32_16x16x32_f16(a0, load_b_frag(wb_out, nt, 0, lane), acc, 0, 0, 0);
            acc = __builtin_amdgcn_mfma_f32_16x16x32_f16(a1, load_b_frag(wb_out, nt, 1, lane), acc, 0, 0, 0);
            int col = (nt << 4) + lrow;
            if (col < C) {
                float b = lin_b[col];
#pragma unroll
                for (int e = 0; e < 4; ++e) {
                    int row = base + (lgrp << 2) + e;
                    out[(size_t)row * C + col] = acc[e] + b;
                }
            }
        }
    }
}

// ---------------- gather raw h rows (conv folded into GRU weights) ----------------
__global__ __launch_bounds__(256) void gather_kernel(const __half* __restrict__ h,
                                                     const int* __restrict__ rowptr,
                                                     const int* __restrict__ col,
                                                     _Float16* __restrict__ agg) {
    int w = (blockIdx.x * 256 + threadIdx.x) >> 6;
    int lane = threadIdx.x & 63;
    if (w >= N_NODES) return;
    int start = rowptr[w], end = rowptr[w + 1];
    int j = lane >> 3, q = lane & 7;
    bool qok = (q < 7);
    int hoff = qok ? (q * 8) : 48;
    float acc0 = 0.f, acc1 = 0.f, acc2 = 0.f, acc3 = 0.f;
    float acc4 = 0.f, acc5 = 0.f, acc6 = 0.f, acc7 = 0.f;

    for (int base = start; base < end; base += 64) {
        int cidx = base + lane;
        int cols = col[cidx < N_EDGES ? cidx : (N_EDGES - 1)];
        int cnt = end - base; if (cnt > 64) cnt = 64;
        int nt8 = (cnt + 7) >> 3;
#pragma unroll 4
        for (int t = 0; t < nt8; ++t) {
            int rel = 8 * t + j;
            int s = __shfl(cols, rel);
            bool valid = qok && (rel < cnt);
            const uint4 v = *reinterpret_cast<const uint4*>(h + (size_t)s * PH + hoff);
            float2 f0 = __half22float2(*reinterpret_cast<const __half2*>(&v.x));
            float2 f1 = __half22float2(*reinterpret_cast<const __half2*>(&v.y));
            float2 f2 = __half22float2(*reinterpret_cast<const __half2*>(&v.z));
            float2 f3 = __half22float2(*reinterpret_cast<const __half2*>(&v.w));
            acc0 += valid ? f0.x : 0.f;  acc1 += valid ? f0.y : 0.f;
            acc2 += valid ? f1.x : 0.f;  acc3 += valid ? f1.y : 0.f;
            acc4 += valid ? f2.x : 0.f;  acc5 += valid ? f2.y : 0.f;
            acc6 += valid ? f3.x : 0.f;  acc7 += valid ? f3.y : 0.f;
        }
    }
#pragma unroll
    for (int s = 8; s <= 32; s <<= 1) {
        acc0 += __shfl_xor(acc0, s); acc1 += __shfl_xor(acc1, s);
        acc2 += __shfl_xor(acc2, s); acc3 += __shfl_xor(acc3, s);
        acc4 += __shfl_xor(acc4, s); acc5 += __shfl_xor(acc5, s);
        acc6 += __shfl_xor(acc6, s); acc7 += __shfl_xor(acc7, s);
    }
    if (j == 0) {
        if (qok) {
            half8 o;
            o[0] = (_Float16)acc0; o[1] = (_Float16)acc1;
            o[2] = (_Float16)acc2; o[3] = (_Float16)acc3;
            o[4] = (_Float16)acc4; o[5] = (_Float16)acc5;
            o[6] = (_Float16)acc6; o[7] = (_Float16)acc7;
            *reinterpret_cast<half8*>(agg + (size_t)w * PH + q * 8) = o;
        } else {
            half8 z = {};
            *reinterpret_cast<half8*>(agg + (size_t)w * PH + 56) = z;
        }
    }
}

extern "C" void kernel_launch(void* const* d_in, const int* in_sizes, int n_in,
                              void* d_out, int out_size, void* d_ws, size_t ws_size,
                              hipStream_t stream) {
    const float* x      = (const float*)d_in[0];
    const int*   ei     = (const int*)  d_in[1];
    const float* conv_w = (const float*)d_in[3];
    const float* w_ih   = (const float*)d_in[4];
    const float* w_hh   = (const float*)d_in[5];
    const float* b_ih   = (const float*)d_in[6];
    const float* b_hh   = (const float*)d_in[7];
    const float* lin_w  = (const float*)d_in[9];
    const float* lin_b  = (const float*)d_in[10];
    float* out = (float*)d_out;

    // layout: h0 | h1 | agg | scratch(NH) | wb | col | rowptr | cnt | off
    // pairs (14.4 MB) spans agg (12.8) + head of scratch — dead after fill; wb untouched
    _Float16* h0  = (_Float16*)d_ws;
    _Float16* h1  = h0 + NH;
    _Float16* agg = h1 + NH;
    _Float16* scratch = agg + NH;              // pairs overflow region
    _Float16* wb  = scratch + NH;
    unsigned int* pairs = (unsigned int*)agg;
    int* col       = (int*)(wb + 13 * 4096);
    int* rowptr    = col + N_EDGES;
    int* cnt       = rowptr + N_NODES + 1;
    int* bucketOff = cnt + NB2;

    const int initBlocks = (NH + 255) / 256;
    const int waveBlocks = (N_NODES * 64 + 255) / 256;
    const int gemmBlocks = (NTILES + 3) / 4;

    init_kernel<<<initBlocks, 256, 0, stream>>>(x, conv_w, w_ih, w_hh, lin_w, h0, wb, cnt);

    partition_kernel<<<EB, 256, 0, stream>>>(ei, cnt, pairs);
    bscan_kernel<<<1, 1024, 0, stream>>>(cnt, bucketOff);
    bucket_fill_kernel<<<NB2, 256, 0, stream>>>(pairs, cnt, bucketOff, rowptr, col);

    // layer 1: gather raw h0; GRU with W_l1-combined gate weights
    gather_kernel<<<waveBlocks, 256, 0, stream>>>((const __half*)h0, rowptr, col, agg);
    gemm_gru<<<gemmBlocks, 256, 0, stream>>>(agg, h0, wb + 0 * 3 * 4096, wb + 9 * 4096,
                                             b_ih, b_hh, h1);
    // layer 2
    gather_kernel<<<waveBlocks, 256, 0, stream>>>((const __half*)h1, rowptr, col, agg);
    gemm_gru<<<gemmBlocks, 256, 0, stream>>>(agg, h1, wb + 1 * 3 * 4096, wb + 9 * 4096,
                                             b_ih, b_hh, h0);
    // layer 3 + out
    gather_kernel<<<waveBlocks, 256, 0, stream>>>((const __half*)h0, rowptr, col, agg);
    gemm_gru_out<<<gemmBlocks, 256, 0, stream>>>(agg, h0, wb + 2 * 3 * 4096, wb + 9 * 4096,
                                                 b_ih, b_hh, wb + 12 * 4096, lin_b, out);
}